// Round 18
// baseline (96.348 us; speedup 1.0000x reference)
//
#include <hip/hip_runtime.h>
#include <hip/hip_bf16.h>
#include <cstdint>
#include <cstddef>

typedef __attribute__((ext_vector_type(8))) short bf16x8;
typedef __attribute__((ext_vector_type(4))) float f32x4;
typedef __attribute__((address_space(3))) void lds_void;
typedef const __attribute__((address_space(1))) void g_void;

constexpr int Bc = 2, Sc = 2048, Dc = 512, Hc = 8, DKc = 64;
constexpr int SPLIT = 2;
constexpr int NKT = Sc / 64;           // 32 k-tiles total
constexpr int KT_PER = NKT / SPLIT;    // 16 per block
constexpr float CSC = 0.18033688011112042f;  // 0.125 * log2(e), folded into Q projection

struct alignas(16) us8 { unsigned short u[8]; };
struct alignas(8) us4 { unsigned short u[4]; };

__device__ __forceinline__ unsigned short f2bf(float x) {
  union { float f; unsigned int u; } v; v.f = x;
  unsigned int r = (v.u + 0x7FFFu + ((v.u >> 16) & 1u)) >> 16;
  return (unsigned short)r;
}

__device__ __forceinline__ float bf2f(unsigned short u) {
  union { unsigned int u; float f; } v; v.u = ((unsigned int)u) << 16;
  return v.f;
}

__device__ __forceinline__ us8 cvt8(float4 a, float4 b) {
  us8 o;
  o.u[0] = f2bf(a.x); o.u[1] = f2bf(a.y); o.u[2] = f2bf(a.z); o.u[3] = f2bf(a.w);
  o.u[4] = f2bf(b.x); o.u[5] = f2bf(b.y); o.u[6] = f2bf(b.z); o.u[7] = f2bf(b.w);
  return o;
}

// ---------------- shared GEMM body: 128x64 tile; A fp32(reg)/bf16(gload_lds); W fp32 reg-converted ----------------
// mode 0: bf16 [M,N] (scaled by osc); 1: bf16 per-batch transposed [b][n][s]; 2: fp32 [M,N].
template<int A_FP32>
__device__ __forceinline__ void gemm_body(
    unsigned short (*As)[64], unsigned short (*Bs)[64],
    const void* Ap, const float* Wp, const float* bias, void* Cp,
    int mode, float osc, int m0, int n0)
{
  constexpr int K = 512, N = 512;
  const int tid = threadIdx.x, lane = tid & 63, w = tid >> 6;
  const int wm = w >> 1, wn = w & 1;                 // wave owns 64m x 32n
  const int colb = lane & 15, hi = lane >> 4, rowb = hi * 4;
  const int swz = (colb & 7) << 4;

  f32x4 acc[4][2];
#pragma unroll
  for (int i = 0; i < 4; ++i)
#pragma unroll
    for (int j = 0; j < 2; ++j) acc[i][j] = (f32x4){0.f, 0.f, 0.f, 0.f};

  const int lrow8 = lane >> 3;
  const int cb = ((lane & 7) * 16) ^ (lrow8 << 4);   // pre-swizzled src col-bytes (bf16 layout)

  for (int k0 = 0; k0 < K; k0 += 64) {
    if (k0) __syncthreads();
    // B staging: fp32 W reg-converted, linear dest + pre-swizzled source
#pragma unroll
    for (int i = 0; i < 2; ++i) {
      const int u = w + i * 4;
      const int row = u * 8 + lrow8;
      const float* src = Wp + (size_t)(n0 + row) * K + k0 + (cb >> 1);
      float4 v0 = *(const float4*)src, v1 = *(const float4*)(src + 4);
      *(us8*)((char*)&Bs[0][0] + u * 1024 + lane * 16) = cvt8(v0, v1);
    }
    // A staging
    if (A_FP32) {
      const float* Af = (const float*)Ap;
#pragma unroll
      for (int i = 0; i < 4; ++i) {
        const int u = w * 4 + i;
        const int row = u * 8 + lrow8;
        const float* src = Af + (size_t)(m0 + row) * K + k0 + (cb >> 1);
        float4 v0 = *(const float4*)src, v1 = *(const float4*)(src + 4);
        *(us8*)((char*)&As[0][0] + u * 1024 + lane * 16) = cvt8(v0, v1);
      }
    } else {
      const unsigned short* Ab = (const unsigned short*)Ap;
#pragma unroll
      for (int i = 0; i < 4; ++i) {
        const int u = w * 4 + i;
        const int row = u * 8 + lrow8;
        const unsigned short* asrc = Ab + (size_t)(m0 + row) * K + k0 + (cb >> 1);
        __builtin_amdgcn_global_load_lds((g_void*)asrc, (lds_void*)((char*)&As[0][0] + u * 1024), 16, 0, 0);
      }
      asm volatile("s_waitcnt vmcnt(0)" ::: "memory");
    }
    __syncthreads();

    char* ab = (char*)&As[0][0];
    char* bb = (char*)&Bs[0][0];
#pragma unroll
    for (int kk = 0; kk < 2; ++kk) {
      bf16x8 af[4], bfr[2];
#pragma unroll
      for (int mf = 0; mf < 4; ++mf) {
        const int ar = wm * 64 + mf * 16 + colb;
        af[mf] = *(const bf16x8*)(ab + ar * 128 + ((kk * 64 + hi * 16) ^ swz));
      }
#pragma unroll
      for (int nf = 0; nf < 2; ++nf) {
        const int br = wn * 32 + nf * 16 + colb;
        bfr[nf] = *(const bf16x8*)(bb + br * 128 + ((kk * 64 + hi * 16) ^ swz));
      }
      __builtin_amdgcn_s_setprio(1);
#pragma unroll
      for (int mf = 0; mf < 4; ++mf)
#pragma unroll
        for (int nf = 0; nf < 2; ++nf)
          acc[mf][nf] = __builtin_amdgcn_mfma_f32_16x16x32_bf16(af[mf], bfr[nf], acc[mf][nf], 0, 0, 0);
      __builtin_amdgcn_s_setprio(0);
    }
  }

#pragma unroll
  for (int nf = 0; nf < 2; ++nf) {
    const int gn = n0 + wn * 32 + nf * 16 + colb;
    const float bv = bias[gn];
    if (mode == 1) {
      unsigned short* Cp2 = (unsigned short*)Cp;
#pragma unroll
      for (int mf = 0; mf < 4; ++mf) {
        const int gm = m0 + wm * 64 + mf * 16 + rowb;
        const int bb_ = gm >> 11, ss = gm & (Sc - 1);
        us4 vv;
#pragma unroll
        for (int rr = 0; rr < 4; ++rr) vv.u[rr] = f2bf(acc[mf][nf][rr] + bv);
        *(us4*)(Cp2 + ((size_t)bb_ * N + gn) * Sc + ss) = vv;
      }
    } else if (mode == 0) {
      unsigned short* Cp2 = (unsigned short*)Cp;
#pragma unroll
      for (int mf = 0; mf < 4; ++mf)
#pragma unroll
        for (int rr = 0; rr < 4; ++rr) {
          const int gm = m0 + wm * 64 + mf * 16 + rowb + rr;
          Cp2[(size_t)gm * N + gn] = f2bf((acc[mf][nf][rr] + bv) * osc);
        }
    } else {
      float* Cp2 = (float*)Cp;
#pragma unroll
      for (int mf = 0; mf < 4; ++mf)
#pragma unroll
        for (int rr = 0; rr < 4; ++rr) {
          const int gm = m0 + wm * 64 + mf * 16 + rowb + rr;
          Cp2[(size_t)gm * N + gn] = acc[mf][nf][rr] + bv;
        }
    }
  }
}

// ---------------- fused launch 1: QKV GEMMs (blocks 0..767) + async-staged g-permute (768..2815) ----------------
struct FArgs {
  const float* g; const int* m; unsigned short* gp;
  const void* A[3]; const float* W[3]; const float* bias[3]; void* C[3];
  int mode[3]; float osc[3];
};

__global__ __launch_bounds__(256)
void fused_qkvpre(FArgs fa)
{
  __shared__ __align__(16) char lds_raw[32768];
  const int bx = blockIdx.x;
  const int tid = threadIdx.x;

  if (bx < 768) {
    unsigned short (*As)[64] = (unsigned short (*)[64])lds_raw;
    unsigned short (*Bs)[64] = (unsigned short (*)[64])(lds_raw + 16384);
    const int z = bx >> 8, r2 = bx & 255;
    const int mx = r2 >> 3, ny = r2 & 7;
    gemm_body<1>(As, Bs, fa.A[z], fa.W[z], fa.bias[z], fa.C[z],
                 fa.mode[z], fa.osc[z], mx * 128, ny * 64);
  } else {
    // async-staged g-permute: stage raw g+mask tiles via gload_lds, gather fragments, coalesced write
    float (*Gs)[64] = (float (*)[64])lds_raw;
    int (*Ms)[64] = (int (*)[64])(lds_raw + 16384);
    const int idx = bx - 768;           // b*1024 + qt*32 + kt
    const int b = idx >> 10, rest = idx & 1023, qt = rest >> 5, kt = rest & 31;
    const int q0 = qt * 64, k0t = kt * 64;
    const int lane = tid & 63, w = tid >> 6;

#pragma unroll
    for (int i = 0; i < 4; ++i) {
      const int unit = w * 4 + i;                        // 0..15
      const int row = unit * 4 + (lane >> 4);            // 0..63
      const int cbyte = ((lane & 15) * 16) ^ ((row & 7) << 4);   // inverse-swizzled source col
      const size_t sbase = ((size_t)(b * Sc + q0 + row)) * Sc + k0t + (cbyte >> 2);
      __builtin_amdgcn_global_load_lds((g_void*)(fa.g + sbase), (lds_void*)((char*)&Gs[0][0] + unit * 1024), 16, 0, 0);
      __builtin_amdgcn_global_load_lds((g_void*)(fa.m + sbase), (lds_void*)((char*)&Ms[0][0] + unit * 1024), 16, 0, 0);
    }
    asm volatile("s_waitcnt vmcnt(0)" ::: "memory");
    __syncthreads();

    const int colb = tid & 15, hi = (tid >> 4) & 3, wid = tid >> 6;
    const int qr = wid * 16 + colb;
    const int q = q0 + qr;
    char* gb = (char*)&Gs[0][0];
    char* mb = (char*)&Ms[0][0];
    unsigned short vals[16];
#pragma unroll
    for (int n = 0; n < 4; ++n) {
      const int addr = qr * 256 + ((n * 64 + hi * 16) ^ ((qr & 7) << 4));
      float4 gv = *(const float4*)(gb + addr);
      int4 mv = *(const int4*)(mb + addr);
      const int kb = k0t + n * 16 + hi * 4;
      const float gg[4] = {gv.x, gv.y, gv.z, gv.w};
      const int mm[4] = {mv.x, mv.y, mv.z, mv.w};
#pragma unroll
      for (int rr = 0; rr < 4; ++rr) {
        const bool allowed = (mm[rr] != 0) || (kb + rr == q);
        vals[n * 4 + rr] = allowed ? (unsigned short)(f2bf(gg[rr]) | 1u) : (unsigned short)0;
      }
    }
    us8* o = (us8*)(fa.gp + (((size_t)idx * 256) + tid) * 16);
    o[0] = *(us8*)&vals[0];
    o[1] = *(us8*)&vals[8];
  }
}

// ---------------- O-projection (A bf16 via gload_lds, W fp32 reg-staged) ----------------
__global__ __launch_bounds__(256)
void gemm_o(const unsigned short* Xb, const float* Wo, const float* bo, float* out)
{
  __shared__ unsigned short As[128][64];
  __shared__ unsigned short Bs[64][64];
  gemm_body<0>(As, Bs, (const void*)Xb, Wo, bo, (void*)out,
               2, 1.0f, blockIdx.x * 128, blockIdx.y * 64);
}

// ---------------- split-K flash attention: fixed-shift softmax + XCD swizzle + static dbuf ----------------
// 1-D grid of 1024; wgid decode co-locates the 16 blocks of one (b,qt) g-group on one XCD.
// Partials: Pacc[blk][d=64][q=64] bf16 (O^T), Pml[blk][64] = l (fp32).
__global__ __launch_bounds__(256, 4)
void attn_split(const unsigned short* __restrict__ Qb,
                const unsigned short* __restrict__ Kb,
                const unsigned short* __restrict__ Vt,
                const unsigned short* __restrict__ Gp,
                unsigned short* __restrict__ Pacc,
                float* __restrict__ Pml)
{
  __shared__ unsigned short Ks[2][64][64];   // [k][dk], XOR-swizzled rows
  __shared__ unsigned short Vs[2][64][64];   // [dk][k], XOR-swizzled rows
  __shared__ unsigned short Ps[4][16][64];   // per-wave P [q][k], XOR-swizzled rows

  const int tid = threadIdx.x, lane = tid & 63, wid = tid >> 6;
  const int wgid = blockIdx.x;
  const int xcd = wgid & 7, rest = wgid >> 3;
  const int mem = rest & 15, ghi = rest >> 4;
  const int g = ghi * 8 + xcd;                // 0..63
  const int b = g >> 5, qt = g & 31;
  const int h = mem >> 1, sp = mem & 1;
  const int bh = b * 8 + h;
  const int q0 = qt * 64;
  const int kt0 = sp * KT_PER;

  const int colb = lane & 15;
  const int hi = lane >> 4;
  const int rowb = hi * 4;
  const int c3s = (colb & 7) << 4;

  bf16x8 qf[2];
  {
    const unsigned short* qp = Qb + ((size_t)(b * Sc + q0 + wid * 16 + colb) * Dc + h * DKc + hi * 8);
    qf[0] = *(const bf16x8*)qp;
    qf[1] = *(const bf16x8*)(qp + 32);
  }

  f32x4 acc[4] = {{0,0,0,0},{0,0,0,0},{0,0,0,0},{0,0,0,0}};   // acc[n][rr] = O^T[n*16+rowb+rr][q]
  float lr0 = 0.f, lr1 = 0.f, lr2 = 0.f, lr3 = 0.f;            // tree-split l partials

  auto stageKV = [&](int bufI, int kt) {
    const int k0 = kt * 64;
#pragma unroll
    for (int i = 0; i < 2; ++i) {
      const int obase = wid * 1024 + i * 4096;
      const int row = (obase >> 7) + (lane >> 3);
      const int cb = ((lane & 7) * 16) ^ ((row & 7) << 4);
      const unsigned short* ksrc = Kb + (size_t)(b * Sc + k0 + row) * Dc + h * DKc + (cb >> 1);
      const unsigned short* vsrc = Vt + ((size_t)b * Dc + h * DKc + row) * Sc + k0 + (cb >> 1);
      __builtin_amdgcn_global_load_lds((g_void*)ksrc, (lds_void*)((char*)&Ks[bufI][0][0] + obase), 16, 0, 0);
      __builtin_amdgcn_global_load_lds((g_void*)vsrc, (lds_void*)((char*)&Vs[bufI][0][0] + obase), 16, 0, 0);
    }
  };

  const unsigned short* gtile = Gp + (((size_t)(b * 1024 + qt * 32)) * 256 + tid) * 16;
  auto loadG = [&](int kt, us8& g0, us8& g1) {
    const us8* p = (const us8*)(gtile + (size_t)kt * 4096);
    g0 = p[0]; g1 = p[1];
  };

  us8 gA0, gA1, gB0, gB1;
  stageKV(0, kt0);
  loadG(kt0, gA0, gA1);
  asm volatile("s_waitcnt vmcnt(0)" ::: "memory");
  __syncthreads();

  char* psbase = (char*)&Ps[wid][0][0];

  auto doTile = [&](int kt, int bufI, us8& gc0, us8& gc1, us8& gn0, us8& gn1) {
    if (kt + 1 < kt0 + KT_PER) {
      stageKV(bufI ^ 1, kt + 1);
      loadG(kt + 1, gn0, gn1);
    }

    f32x4 sf[4] = {{0,0,0,0},{0,0,0,0},{0,0,0,0},{0,0,0,0}};
    char* ksb = (char*)&Ks[bufI][0][0];
    __builtin_amdgcn_s_setprio(1);
#pragma unroll
    for (int kk = 0; kk < 2; ++kk) {
#pragma unroll
      for (int n = 0; n < 4; ++n) {
        const int krow = n * 16 + colb;
        bf16x8 kf = *(const bf16x8*)(ksb + krow * 128 + ((kk * 64 + hi * 16) ^ ((krow & 7) << 4)));
        sf[n] = __builtin_amdgcn_mfma_f32_16x16x32_bf16(kf, qf[kk], sf[n], 0, 0, 0);
      }
    }
    __builtin_amdgcn_s_setprio(0);

    // fixed-shift softmax: p = exp2(s2); gating via g LSB; l in 4 independent partials
    unsigned int pw[8];
#pragma unroll
    for (int n = 0; n < 4; ++n) {
      float lacc = 0.f;
#pragma unroll
      for (int s2 = 0; s2 < 2; ++s2) {
        const int jv = n * 4 + s2 * 2;
        const unsigned short u0 = (jv < 8) ? gc0.u[jv] : gc1.u[jv - 8];
        const unsigned short u1 = (jv + 1 < 8) ? gc0.u[jv + 1] : gc1.u[jv + 1 - 8];
        const float p0 = __builtin_amdgcn_exp2f(sf[n][s2 * 2]);
        const float p1 = __builtin_amdgcn_exp2f(sf[n][s2 * 2 + 1]);
        lacc = fmaf(p0, (float)(u0 & 1u), lacc);
        lacc = fmaf(p1, (float)(u1 & 1u), lacc);
        const float q0v = p0 * bf2f(u0), q1v = p1 * bf2f(u1);
        asm("v_cvt_pk_bf16_f32 %0, %1, %2" : "=v"(pw[n * 2 + s2]) : "v"(q0v), "v"(q1v));
      }
      if (n == 0) lr0 += lacc; else if (n == 1) lr1 += lacc;
      else if (n == 2) lr2 += lacc; else lr3 += lacc;
    }

#pragma unroll
    for (int n = 0; n < 4; ++n) {
      const unsigned long long w64 = ((unsigned long long)pw[n * 2 + 1] << 32) | pw[n * 2];
      *(unsigned long long*)(psbase + colb * 128 + ((n * 32 + hi * 8) ^ c3s)) = w64;
    }

    char* vsb = (char*)&Vs[bufI][0][0];
    __builtin_amdgcn_s_setprio(1);
#pragma unroll
    for (int kk = 0; kk < 2; ++kk) {
      bf16x8 pf = *(const bf16x8*)(psbase + colb * 128 + ((kk * 64 + hi * 16) ^ c3s));
#pragma unroll
      for (int n = 0; n < 4; ++n) {
        const int vrow = n * 16 + colb;
        bf16x8 vf = *(const bf16x8*)(vsb + vrow * 128 + ((kk * 64 + hi * 16) ^ ((vrow & 7) << 4)));
        acc[n] = __builtin_amdgcn_mfma_f32_16x16x32_bf16(vf, pf, acc[n], 0, 0, 0);
      }
    }
    __builtin_amdgcn_s_setprio(0);

    asm volatile("s_waitcnt vmcnt(0)" ::: "memory");
    __syncthreads();
  };

  for (int j = 0; j < KT_PER; j += 2) {
    doTile(kt0 + j,     0, gA0, gA1, gB0, gB1);
    doTile(kt0 + j + 1, 1, gB0, gB1, gA0, gA1);
  }

  float lrun = (lr0 + lr1) + (lr2 + lr3);
  lrun += __shfl_xor(lrun, 16);
  lrun += __shfl_xor(lrun, 32);

  const size_t blin = ((size_t)bh * 32 + qt) * SPLIT + sp;
  unsigned short* pa = Pacc + blin * 4096;
#pragma unroll
  for (int n = 0; n < 4; ++n)
#pragma unroll
    for (int rr = 0; rr < 4; ++rr)
      pa[(size_t)(n * 16 + rowb + rr) * 64 + wid * 16 + colb] = f2bf(acc[n][rr]);
  if (hi == 0) Pml[blin * 64 + wid * 16 + colb] = lrun;
}

// ---------------- recombine split partials -> bf16 X (plain sum; fixed shift) ----------------
__global__ __launch_bounds__(256)
void attn_reduce(const unsigned short* __restrict__ Pacc, const float* __restrict__ Pml,
                 unsigned short* __restrict__ Xb)
{
  const int gidx = blockIdx.x;      // bh*32 + qt
  const int bh = gidx >> 5, qt = gidx & 31;
  const int b = bh >> 3, h = bh & 7;
  const int tid = threadIdx.x;
  const int qi = tid & 63;
  const int d0 = (tid >> 6) * 16;
  const size_t pb = (size_t)gidx * SPLIT;

  float denom = 0.f;
#pragma unroll
  for (int s = 0; s < SPLIT; ++s) denom += Pml[(pb + s) * 64 + qi];
  const float inv = 1.0f / denom;

  unsigned short vals[16];
#pragma unroll
  for (int j = 0; j < 16; ++j) {
    float a = 0.f;
#pragma unroll
    for (int s = 0; s < SPLIT; ++s)
      a += bf2f(Pacc[(pb + s) * 4096 + (size_t)(d0 + j) * 64 + qi]);
    vals[j] = f2bf(a * inv);
  }
  unsigned short* xp = Xb + ((size_t)(b * Sc) + qt * 64 + qi) * Dc + h * DKc + d0;
  *(us8*)xp = *(us8*)&vals[0];
  *(us8*)(xp + 8) = *(us8*)&vals[8];
}

extern "C" void kernel_launch(void* const* d_in, const int* in_sizes, int n_in,
                              void* d_out, int out_size, void* d_ws, size_t ws_size,
                              hipStream_t stream)
{
  const float* query = (const float*)d_in[0];
  const float* key_  = (const float*)d_in[1];
  const float* value = (const float*)d_in[2];
  const float* gprob = (const float*)d_in[3];
  const int*   mask  = (const int*)d_in[4];
  const float* Wq = (const float*)d_in[5];
  const float* bq = (const float*)d_in[6];
  const float* Wk = (const float*)d_in[7];
  const float* bk = (const float*)d_in[8];
  const float* Wv = (const float*)d_in[9];
  const float* bv = (const float*)d_in[10];
  const float* Wo = (const float*)d_in[11];
  const float* bo = (const float*)d_in[12];
  float* out = (float*)d_out;

  const size_t elems = (size_t)Bc * Sc * Dc;     // 2 Mi
  const size_t gelems = (size_t)Bc * Sc * Sc;    // 8 Mi

  char* base = (char*)d_ws;
  unsigned short* Qb = (unsigned short*)(base);                    // 4 MB
  unsigned short* Kb = Qb + elems;                                 // 4 MB
  unsigned short* Vt = Kb + elems;                                 // 4 MB
  unsigned short* Xb = Vt + elems;                                 // 4 MB
  unsigned short* Gp = Xb + elems;                                 // 16.8 MB
  unsigned short* Pacc = Gp + gelems;                              // 8.4 MB bf16 partials
  float* Pml = (float*)(Pacc + (size_t)(Bc * Hc) * 32 * SPLIT * 4096);  // 0.26 MB

  // launch 1: fused QKV GEMMs + async-staged g-permute
  FArgs fa;
  fa.g = gprob; fa.m = mask; fa.gp = Gp;
  fa.A[0] = (const void*)query; fa.W[0] = Wq; fa.bias[0] = bq; fa.C[0] = (void*)Qb; fa.mode[0] = 0; fa.osc[0] = CSC;
  fa.A[1] = (const void*)key_;  fa.W[1] = Wk; fa.bias[1] = bk; fa.C[1] = (void*)Kb; fa.mode[1] = 0; fa.osc[1] = 1.0f;
  fa.A[2] = (const void*)value; fa.W[2] = Wv; fa.bias[2] = bv; fa.C[2] = (void*)Vt; fa.mode[2] = 1; fa.osc[2] = 1.0f;
  hipLaunchKernelGGL(fused_qkvpre, dim3(768 + 2048), dim3(256), 0, stream, fa);

  // launch 2: attention (1-D XCD-swizzled grid)
  hipLaunchKernelGGL(attn_split, dim3(1024), dim3(256), 0, stream, Qb, Kb, Vt, Gp, Pacc, Pml);

  // launch 3: recombine
  hipLaunchKernelGGL(attn_reduce, dim3(Bc * Hc * 32), dim3(256), 0, stream, Pacc, Pml, Xb);

  // launch 4: output projection
  hipLaunchKernelGGL(gemm_o, dim3(32, 8), dim3(256), 0, stream, Xb, Wo, bo, out);
}

// Round 19
// 91.675 us; speedup vs baseline: 1.0510x; 1.0510x over previous
//
#include <hip/hip_runtime.h>
#include <hip/hip_bf16.h>
#include <cstdint>
#include <cstddef>

typedef __attribute__((ext_vector_type(8))) short bf16x8;
typedef __attribute__((ext_vector_type(4))) float f32x4;
typedef __attribute__((address_space(3))) void lds_void;
typedef const __attribute__((address_space(1))) void g_void;

constexpr int Bc = 2, Sc = 2048, Dc = 512, Hc = 8, DKc = 64;
constexpr int SPLIT = 2;
constexpr int NKT = Sc / 64;           // 32 k-tiles total
constexpr int KT_PER = NKT / SPLIT;    // 16 per block
constexpr float CSC = 0.18033688011112042f;  // 0.125 * log2(e), folded into Q projection

struct alignas(16) us8 { unsigned short u[8]; };
struct alignas(8) us4 { unsigned short u[4]; };

__device__ __forceinline__ unsigned short f2bf(float x) {
  union { float f; unsigned int u; } v; v.f = x;
  unsigned int r = (v.u + 0x7FFFu + ((v.u >> 16) & 1u)) >> 16;
  return (unsigned short)r;
}

__device__ __forceinline__ float bf2f(unsigned short u) {
  union { unsigned int u; float f; } v; v.u = ((unsigned int)u) << 16;
  return v.f;
}

__device__ __forceinline__ us8 cvt8(float4 a, float4 b) {
  us8 o;
  o.u[0] = f2bf(a.x); o.u[1] = f2bf(a.y); o.u[2] = f2bf(a.z); o.u[3] = f2bf(a.w);
  o.u[4] = f2bf(b.x); o.u[5] = f2bf(b.y); o.u[6] = f2bf(b.z); o.u[7] = f2bf(b.w);
  return o;
}

// ---------------- prepass: g-permute via ASYNC-staged LDS tiles + weight fp32->bf16 ----------------
// blocks 0..2047: g tiles; blocks 2048..2079: weight conversion.  (round-16 proven)
struct WArgs { const float* wsrc[4]; unsigned short* wdst[4]; };

__global__ __launch_bounds__(256)
void prepass(const float* __restrict__ g, const int* __restrict__ m,
             unsigned short* __restrict__ gp, WArgs wa)
{
  __shared__ float Gs[64][64];   // 16 KB, XOR-swizzled granules (16B, phase (row&7)<<4)
  __shared__ int   Ms[64][64];   // 16 KB, same swizzle
  const int bx = blockIdx.x;
  const int tid = threadIdx.x;
  if (bx < 2048) {
    const int idx = bx;                 // b*1024 + qt*32 + kt
    const int b = idx >> 10, rest = idx & 1023, qt = rest >> 5, kt = rest & 31;
    const int q0 = qt * 64, k0t = kt * 64;
    const int lane = tid & 63, w = tid >> 6;

#pragma unroll
    for (int i = 0; i < 4; ++i) {
      const int unit = w * 4 + i;                        // 0..15
      const int row = unit * 4 + (lane >> 4);            // 0..63
      const int cbyte = ((lane & 15) * 16) ^ ((row & 7) << 4);   // inverse-swizzled source col
      const size_t sbase = ((size_t)(b * Sc + q0 + row)) * Sc + k0t + (cbyte >> 2);
      __builtin_amdgcn_global_load_lds((g_void*)(g + sbase), (lds_void*)((char*)&Gs[0][0] + unit * 1024), 16, 0, 0);
      __builtin_amdgcn_global_load_lds((g_void*)(m + sbase), (lds_void*)((char*)&Ms[0][0] + unit * 1024), 16, 0, 0);
    }
    asm volatile("s_waitcnt vmcnt(0)" ::: "memory");
    __syncthreads();

    const int colb = tid & 15, hi = (tid >> 4) & 3, wid = tid >> 6;
    const int qr = wid * 16 + colb;
    const int q = q0 + qr;
    char* gb = (char*)&Gs[0][0];
    char* mb = (char*)&Ms[0][0];
    unsigned short vals[16];
#pragma unroll
    for (int n = 0; n < 4; ++n) {
      const int addr = qr * 256 + ((n * 64 + hi * 16) ^ ((qr & 7) << 4));
      float4 gv = *(const float4*)(gb + addr);
      int4 mv = *(const int4*)(mb + addr);
      const int kb = k0t + n * 16 + hi * 4;
      const float gg[4] = {gv.x, gv.y, gv.z, gv.w};
      const int mm[4] = {mv.x, mv.y, mv.z, mv.w};
#pragma unroll
      for (int rr = 0; rr < 4; ++rr) {
        const bool allowed = (mm[rr] != 0) || (kb + rr == q);
        vals[n * 4 + rr] = allowed ? (unsigned short)(f2bf(gg[rr]) | 1u) : (unsigned short)0;
      }
    }
    us8* o = (us8*)(gp + (((size_t)idx * 256) + tid) * 16);
    o[0] = *(us8*)&vals[0];
    o[1] = *(us8*)&vals[8];
  } else {
    const int r = bx - 2048;            // 0..31
    const int wi = r >> 3, sub = r & 7;
    const float* s = wa.wsrc[wi];
    unsigned short* d = wa.wdst[wi];
#pragma unroll
    for (int t = 0; t < 16; ++t) {
      const int i = sub * 4096 + t * 256 + tid;
      float4 a = ((const float4*)s)[(size_t)i * 2];
      float4 b2 = ((const float4*)s)[(size_t)i * 2 + 1];
      ((us8*)d)[i] = cvt8(a, b2);
    }
  }
}

// ---------------- 128x64-tile bf16 NT GEMM (W bf16 via gload_lds) — QKV projections ----------------
struct GArgs {
  const void* A[3];
  const unsigned short* W[3];
  const float* bias[3];
  void* C[3];
  int mode[3];
  float osc[3];
};

template<int A_FP32>
__global__ __launch_bounds__(256)
void gemm_bn64(GArgs ga)
{
  __shared__ unsigned short As[128][64];
  __shared__ unsigned short Bs[64][64];

  constexpr int K = 512, N = 512;
  const int z = blockIdx.z;
  const unsigned short* Wp = ga.W[z];
  const float* bias = ga.bias[z];
  const int mode = ga.mode[z];
  const float osc = ga.osc[z];

  const int tid = threadIdx.x, lane = tid & 63, w = tid >> 6;
  const int m0 = blockIdx.x * 128, n0 = blockIdx.y * 64;
  const int wm = w >> 1, wn = w & 1;
  const int colb = lane & 15, hi = lane >> 4, rowb = hi * 4;
  const int swz = (colb & 7) << 4;

  f32x4 acc[4][2];
#pragma unroll
  for (int i = 0; i < 4; ++i)
#pragma unroll
    for (int j = 0; j < 2; ++j) acc[i][j] = (f32x4){0.f, 0.f, 0.f, 0.f};

  const int lrow8 = lane >> 3;
  const int cb = ((lane & 7) * 16) ^ (lrow8 << 4);

  for (int k0 = 0; k0 < K; k0 += 64) {
    if (k0) __syncthreads();
#pragma unroll
    for (int i = 0; i < 2; ++i) {
      const int u = w + i * 4;
      const int row = u * 8 + lrow8;
      const unsigned short* bsrc = Wp + (size_t)(n0 + row) * K + k0 + (cb >> 1);
      __builtin_amdgcn_global_load_lds((g_void*)bsrc, (lds_void*)((char*)&Bs[0][0] + u * 1024), 16, 0, 0);
    }
    if (A_FP32) {
      const float* Af = (const float*)ga.A[z];
#pragma unroll
      for (int i = 0; i < 4; ++i) {
        const int u = w * 4 + i;
        const int row = u * 8 + lrow8;
        const float* src = Af + (size_t)(m0 + row) * K + k0 + (cb >> 1);
        float4 v0 = *(const float4*)src, v1 = *(const float4*)(src + 4);
        *(us8*)((char*)&As[0][0] + u * 1024 + lane * 16) = cvt8(v0, v1);
      }
    } else {
      const unsigned short* Ab = (const unsigned short*)ga.A[z];
#pragma unroll
      for (int i = 0; i < 4; ++i) {
        const int u = w * 4 + i;
        const int row = u * 8 + lrow8;
        const unsigned short* asrc = Ab + (size_t)(m0 + row) * K + k0 + (cb >> 1);
        __builtin_amdgcn_global_load_lds((g_void*)asrc, (lds_void*)((char*)&As[0][0] + u * 1024), 16, 0, 0);
      }
    }
    asm volatile("s_waitcnt vmcnt(0)" ::: "memory");
    __syncthreads();

    char* ab = (char*)&As[0][0];
    char* bb = (char*)&Bs[0][0];
#pragma unroll
    for (int kk = 0; kk < 2; ++kk) {
      bf16x8 af[4], bfr[2];
#pragma unroll
      for (int mf = 0; mf < 4; ++mf) {
        const int ar = wm * 64 + mf * 16 + colb;
        af[mf] = *(const bf16x8*)(ab + ar * 128 + ((kk * 64 + hi * 16) ^ swz));
      }
#pragma unroll
      for (int nf = 0; nf < 2; ++nf) {
        const int br = wn * 32 + nf * 16 + colb;
        bfr[nf] = *(const bf16x8*)(bb + br * 128 + ((kk * 64 + hi * 16) ^ swz));
      }
      __builtin_amdgcn_s_setprio(1);
#pragma unroll
      for (int mf = 0; mf < 4; ++mf)
#pragma unroll
        for (int nf = 0; nf < 2; ++nf)
          acc[mf][nf] = __builtin_amdgcn_mfma_f32_16x16x32_bf16(af[mf], bfr[nf], acc[mf][nf], 0, 0, 0);
      __builtin_amdgcn_s_setprio(0);
    }
  }

#pragma unroll
  for (int nf = 0; nf < 2; ++nf) {
    const int gn = n0 + wn * 32 + nf * 16 + colb;
    const float bv = bias[gn];
    if (mode == 1) {
      unsigned short* Cp = (unsigned short*)ga.C[z];
#pragma unroll
      for (int mf = 0; mf < 4; ++mf) {
        const int gm = m0 + wm * 64 + mf * 16 + rowb;
        const int bb_ = gm >> 11, ss = gm & (Sc - 1);
        us4 vv;
#pragma unroll
        for (int rr = 0; rr < 4; ++rr) vv.u[rr] = f2bf(acc[mf][nf][rr] + bv);
        *(us4*)(Cp + ((size_t)bb_ * N + gn) * Sc + ss) = vv;
      }
    } else if (mode == 0) {
      unsigned short* Cp = (unsigned short*)ga.C[z];
#pragma unroll
      for (int mf = 0; mf < 4; ++mf)
#pragma unroll
        for (int rr = 0; rr < 4; ++rr) {
          const int gm = m0 + wm * 64 + mf * 16 + rowb + rr;
          Cp[(size_t)gm * N + gn] = f2bf((acc[mf][nf][rr] + bv) * osc);
        }
    } else {
      float* Cp = (float*)ga.C[z];
#pragma unroll
      for (int mf = 0; mf < 4; ++mf)
#pragma unroll
        for (int rr = 0; rr < 4; ++rr) {
          const int gm = m0 + wm * 64 + mf * 16 + rowb + rr;
          Cp[(size_t)gm * N + gn] = acc[mf][nf][rr] + bv;
        }
    }
  }
}

// ---------------- O-projection with fused split-recombine in A-staging ----------------
// A = (P0 + P1) / (l0 + l1), P* bf16 [b][q][D] (X-layout per split), l fp32 [sp][bh][S].
__global__ __launch_bounds__(256)
void gemm_po(const unsigned short* __restrict__ P0, const unsigned short* __restrict__ P1,
             const float* __restrict__ Lml, const unsigned short* __restrict__ Wp,
             const float* __restrict__ bias, float* __restrict__ out)
{
  __shared__ unsigned short As[128][64];
  __shared__ unsigned short Bs[64][64];

  constexpr int K = 512, N = 512;
  const int tid = threadIdx.x, lane = tid & 63, w = tid >> 6;
  const int m0 = blockIdx.x * 128, n0 = blockIdx.y * 64;
  const int wm = w >> 1, wn = w & 1;
  const int colb = lane & 15, hi = lane >> 4, rowb = hi * 4;
  const int swz = (colb & 7) << 4;

  f32x4 acc[4][2];
#pragma unroll
  for (int i = 0; i < 4; ++i)
#pragma unroll
    for (int j = 0; j < 2; ++j) acc[i][j] = (f32x4){0.f, 0.f, 0.f, 0.f};

  const int lrow8 = lane >> 3;
  const int cb = ((lane & 7) * 16) ^ (lrow8 << 4);

  for (int k0 = 0; k0 < K; k0 += 64) {
    if (k0) __syncthreads();
#pragma unroll
    for (int i = 0; i < 2; ++i) {
      const int u = w + i * 4;
      const int row = u * 8 + lrow8;
      const unsigned short* bsrc = Wp + (size_t)(n0 + row) * K + k0 + (cb >> 1);
      __builtin_amdgcn_global_load_lds((g_void*)bsrc, (lds_void*)((char*)&Bs[0][0] + u * 1024), 16, 0, 0);
    }
    // A staging: combine split partials + scale
    const int h = k0 >> 6;
#pragma unroll
    for (int i = 0; i < 4; ++i) {
      const int u = w * 4 + i;
      const int row = u * 8 + lrow8;
      const int gm = m0 + row;
      const int bb2 = gm >> 11, qq = gm & (Sc - 1);
      const size_t off = (size_t)gm * K + k0 + (cb >> 1);
      us8 p0 = *(const us8*)(P0 + off);
      us8 p1 = *(const us8*)(P1 + off);
      const float l0 = Lml[(size_t)(bb2 * 8 + h) * Sc + qq];
      const float l1 = Lml[(size_t)(16 + bb2 * 8 + h) * Sc + qq];
      const float inv = 1.0f / (l0 + l1);
      us8 o;
#pragma unroll
      for (int j = 0; j < 8; ++j)
        o.u[j] = f2bf((bf2f(p0.u[j]) + bf2f(p1.u[j])) * inv);
      *(us8*)((char*)&As[0][0] + u * 1024 + lane * 16) = o;
    }
    asm volatile("s_waitcnt vmcnt(0)" ::: "memory");
    __syncthreads();

    char* ab = (char*)&As[0][0];
    char* bb = (char*)&Bs[0][0];
#pragma unroll
    for (int kk = 0; kk < 2; ++kk) {
      bf16x8 af[4], bfr[2];
#pragma unroll
      for (int mf = 0; mf < 4; ++mf) {
        const int ar = wm * 64 + mf * 16 + colb;
        af[mf] = *(const bf16x8*)(ab + ar * 128 + ((kk * 64 + hi * 16) ^ swz));
      }
#pragma unroll
      for (int nf = 0; nf < 2; ++nf) {
        const int br = wn * 32 + nf * 16 + colb;
        bfr[nf] = *(const bf16x8*)(bb + br * 128 + ((kk * 64 + hi * 16) ^ swz));
      }
      __builtin_amdgcn_s_setprio(1);
#pragma unroll
      for (int mf = 0; mf < 4; ++mf)
#pragma unroll
        for (int nf = 0; nf < 2; ++nf)
          acc[mf][nf] = __builtin_amdgcn_mfma_f32_16x16x32_bf16(af[mf], bfr[nf], acc[mf][nf], 0, 0, 0);
      __builtin_amdgcn_s_setprio(0);
    }
  }

#pragma unroll
  for (int nf = 0; nf < 2; ++nf) {
    const int gn = n0 + wn * 32 + nf * 16 + colb;
    const float bv = bias[gn];
#pragma unroll
    for (int mf = 0; mf < 4; ++mf)
#pragma unroll
      for (int rr = 0; rr < 4; ++rr) {
        const int gm = m0 + wm * 64 + mf * 16 + rowb + rr;
        out[(size_t)gm * N + gn] = acc[mf][nf][rr] + bv;
      }
  }
}

// ---------------- split-K flash attention: fixed-shift softmax + XCD swizzle + static dbuf ----------------
// Writes X-layout partials: Pout[sp][b][q][D] bf16, Pml[sp][bh][S] fp32.
__global__ __launch_bounds__(256, 4)
void attn_split(const unsigned short* __restrict__ Qb,
                const unsigned short* __restrict__ Kb,
                const unsigned short* __restrict__ Vt,
                const unsigned short* __restrict__ Gp,
                unsigned short* __restrict__ Pout,
                float* __restrict__ Pml)
{
  __shared__ unsigned short Ks[2][64][64];   // [k][dk], XOR-swizzled rows
  __shared__ unsigned short Vs[2][64][64];   // [dk][k], XOR-swizzled rows
  __shared__ unsigned short Ps[4][16][64];   // per-wave P [q][k], XOR-swizzled rows

  const int tid = threadIdx.x, lane = tid & 63, wid = tid >> 6;
  const int wgid = blockIdx.x;
  const int xcd = wgid & 7, rest = wgid >> 3;
  const int mem = rest & 15, ghi = rest >> 4;
  const int g = ghi * 8 + xcd;                // 0..63
  const int b = g >> 5, qt = g & 31;
  const int h = mem >> 1, sp = mem & 1;
  const int bh = b * 8 + h;
  const int q0 = qt * 64;
  const int kt0 = sp * KT_PER;

  const int colb = lane & 15;
  const int hi = lane >> 4;
  const int c3s = (colb & 7) << 4;

  bf16x8 qf[2];
  {
    const unsigned short* qp = Qb + ((size_t)(b * Sc + q0 + wid * 16 + colb) * Dc + h * DKc + hi * 8);
    qf[0] = *(const bf16x8*)qp;
    qf[1] = *(const bf16x8*)(qp + 32);
  }

  f32x4 acc[4] = {{0,0,0,0},{0,0,0,0},{0,0,0,0},{0,0,0,0}};   // acc[n][rr] = O^T[n*16+hi*4+rr][q]
  float lr0 = 0.f, lr1 = 0.f, lr2 = 0.f, lr3 = 0.f;            // tree-split l partials

  auto stageKV = [&](int bufI, int kt) {
    const int k0 = kt * 64;
#pragma unroll
    for (int i = 0; i < 2; ++i) {
      const int obase = wid * 1024 + i * 4096;
      const int row = (obase >> 7) + (lane >> 3);
      const int cbk = ((lane & 7) * 16) ^ ((row & 7) << 4);
      const unsigned short* ksrc = Kb + (size_t)(b * Sc + k0 + row) * Dc + h * DKc + (cbk >> 1);
      const unsigned short* vsrc = Vt + ((size_t)b * Dc + h * DKc + row) * Sc + k0 + (cbk >> 1);
      __builtin_amdgcn_global_load_lds((g_void*)ksrc, (lds_void*)((char*)&Ks[bufI][0][0] + obase), 16, 0, 0);
      __builtin_amdgcn_global_load_lds((g_void*)vsrc, (lds_void*)((char*)&Vs[bufI][0][0] + obase), 16, 0, 0);
    }
  };

  const unsigned short* gtile = Gp + (((size_t)(b * 1024 + qt * 32)) * 256 + tid) * 16;
  auto loadG = [&](int kt, us8& g0, us8& g1) {
    const us8* p = (const us8*)(gtile + (size_t)kt * 4096);
    g0 = p[0]; g1 = p[1];
  };

  us8 gA0, gA1, gB0, gB1;
  stageKV(0, kt0);
  loadG(kt0, gA0, gA1);
  asm volatile("s_waitcnt vmcnt(0)" ::: "memory");
  __syncthreads();

  char* psbase = (char*)&Ps[wid][0][0];

  auto doTile = [&](int kt, int bufI, us8& gc0, us8& gc1, us8& gn0, us8& gn1) {
    if (kt + 1 < kt0 + KT_PER) {
      stageKV(bufI ^ 1, kt + 1);
      loadG(kt + 1, gn0, gn1);
    }

    f32x4 sf[4] = {{0,0,0,0},{0,0,0,0},{0,0,0,0},{0,0,0,0}};
    char* ksb = (char*)&Ks[bufI][0][0];
    __builtin_amdgcn_s_setprio(1);
#pragma unroll
    for (int kk = 0; kk < 2; ++kk) {
#pragma unroll
      for (int n = 0; n < 4; ++n) {
        const int krow = n * 16 + colb;
        bf16x8 kf = *(const bf16x8*)(ksb + krow * 128 + ((kk * 64 + hi * 16) ^ ((krow & 7) << 4)));
        sf[n] = __builtin_amdgcn_mfma_f32_16x16x32_bf16(kf, qf[kk], sf[n], 0, 0, 0);
      }
    }
    __builtin_amdgcn_s_setprio(0);

    // fixed-shift softmax: p = exp2(s2); gating via g LSB; l in 4 independent partials
    unsigned int pw[8];
#pragma unroll
    for (int n = 0; n < 4; ++n) {
      float lacc = 0.f;
#pragma unroll
      for (int s2 = 0; s2 < 2; ++s2) {
        const int jv = n * 4 + s2 * 2;
        const unsigned short u0 = (jv < 8) ? gc0.u[jv] : gc1.u[jv - 8];
        const unsigned short u1 = (jv + 1 < 8) ? gc0.u[jv + 1] : gc1.u[jv + 1 - 8];
        const float p0 = __builtin_amdgcn_exp2f(sf[n][s2 * 2]);
        const float p1 = __builtin_amdgcn_exp2f(sf[n][s2 * 2 + 1]);
        lacc = fmaf(p0, (float)(u0 & 1u), lacc);
        lacc = fmaf(p1, (float)(u1 & 1u), lacc);
        const float q0v = p0 * bf2f(u0), q1v = p1 * bf2f(u1);
        asm("v_cvt_pk_bf16_f32 %0, %1, %2" : "=v"(pw[n * 2 + s2]) : "v"(q0v), "v"(q1v));
      }
      if (n == 0) lr0 += lacc; else if (n == 1) lr1 += lacc;
      else if (n == 2) lr2 += lacc; else lr3 += lacc;
    }

#pragma unroll
    for (int n = 0; n < 4; ++n) {
      const unsigned long long w64 = ((unsigned long long)pw[n * 2 + 1] << 32) | pw[n * 2];
      *(unsigned long long*)(psbase + colb * 128 + ((n * 32 + hi * 8) ^ c3s)) = w64;
    }

    char* vsb = (char*)&Vs[bufI][0][0];
    __builtin_amdgcn_s_setprio(1);
#pragma unroll
    for (int kk = 0; kk < 2; ++kk) {
      bf16x8 pf = *(const bf16x8*)(psbase + colb * 128 + ((kk * 64 + hi * 16) ^ c3s));
#pragma unroll
      for (int n = 0; n < 4; ++n) {
        const int vrow = n * 16 + colb;
        bf16x8 vf = *(const bf16x8*)(vsb + vrow * 128 + ((kk * 64 + hi * 16) ^ ((vrow & 7) << 4)));
        acc[n] = __builtin_amdgcn_mfma_f32_16x16x32_bf16(vf, pf, acc[n], 0, 0, 0);
      }
    }
    __builtin_amdgcn_s_setprio(0);

    asm volatile("s_waitcnt vmcnt(0)" ::: "memory");
    __syncthreads();
  };

  for (int j = 0; j < KT_PER; j += 2) {
    doTile(kt0 + j,     0, gA0, gA1, gB0, gB1);
    doTile(kt0 + j + 1, 1, gB0, gB1, gA0, gA1);
  }

  // l: combine partials + cross-lane reduce
  float lrun = (lr0 + lr1) + (lr2 + lr3);
  lrun += __shfl_xor(lrun, 16);
  lrun += __shfl_xor(lrun, 32);

  // epilogue: transpose O^T regs -> X-layout rows via wave-private Ps
#pragma unroll
  for (int n = 0; n < 4; ++n) {
    unsigned int pw0, pw1;
    asm("v_cvt_pk_bf16_f32 %0, %1, %2" : "=v"(pw0) : "v"(acc[n][0]), "v"(acc[n][1]));
    asm("v_cvt_pk_bf16_f32 %0, %1, %2" : "=v"(pw1) : "v"(acc[n][2]), "v"(acc[n][3]));
    const unsigned long long w64 = ((unsigned long long)pw1 << 32) | pw0;
    *(unsigned long long*)(psbase + colb * 128 + ((n * 32 + hi * 8) ^ c3s)) = w64;
  }
  const int qrow = lane >> 2;          // 0..15 local q
  const int dseg = (lane & 3) * 16;    // 0,16,32,48
  const int qsw = (qrow & 7) << 4;
  us8 o0 = *(const us8*)(psbase + qrow * 128 + ((dseg * 2) ^ qsw));
  us8 o1 = *(const us8*)(psbase + qrow * 128 + ((dseg * 2 + 16) ^ qsw));
  unsigned short* xp = Pout + (size_t)sp * ((size_t)Bc * Sc * Dc)
                     + ((size_t)(b * Sc) + q0 + wid * 16 + qrow) * Dc + h * DKc + dseg;
  *(us8*)xp = o0;
  *(us8*)(xp + 8) = o1;
  if (hi == 0) Pml[((size_t)sp * 16 + bh) * Sc + q0 + wid * 16 + colb] = lrun;
}

extern "C" void kernel_launch(void* const* d_in, const int* in_sizes, int n_in,
                              void* d_out, int out_size, void* d_ws, size_t ws_size,
                              hipStream_t stream)
{
  const float* query = (const float*)d_in[0];
  const float* key_  = (const float*)d_in[1];
  const float* value = (const float*)d_in[2];
  const float* gprob = (const float*)d_in[3];
  const int*   mask  = (const int*)d_in[4];
  const float* Wq = (const float*)d_in[5];
  const float* bq = (const float*)d_in[6];
  const float* Wk = (const float*)d_in[7];
  const float* bk = (const float*)d_in[8];
  const float* Wv = (const float*)d_in[9];
  const float* bv = (const float*)d_in[10];
  const float* Wo = (const float*)d_in[11];
  const float* bo = (const float*)d_in[12];
  float* out = (float*)d_out;

  const size_t elems = (size_t)Bc * Sc * Dc;     // 2 Mi
  const size_t gelems = (size_t)Bc * Sc * Sc;    // 8 Mi
  const size_t welems = (size_t)Dc * Dc;         // 256 Ki

  char* base = (char*)d_ws;
  unsigned short* Qb = (unsigned short*)(base);                    // 4 MB
  unsigned short* Kb = Qb + elems;                                 // 4 MB
  unsigned short* Vt = Kb + elems;                                 // 4 MB
  unsigned short* Gp = Vt + elems;                                 // 16.8 MB
  unsigned short* Pout = Gp + gelems;                              // 2 x 4 MB (X-layout partials)
  float* Pml = (float*)(Pout + 2 * elems);                         // 256 KB
  unsigned short* Wqb = (unsigned short*)(Pml + 2 * 16 * Sc);      // 4 x 0.5 MB bf16 weights
  unsigned short* Wkb = Wqb + welems;
  unsigned short* Wvb = Wkb + welems;
  unsigned short* Wob = Wvb + welems;

  // launch 1: fused prepass (async g-permute + weight conversions)
  WArgs wa;
  wa.wsrc[0] = Wq; wa.wdst[0] = Wqb;
  wa.wsrc[1] = Wk; wa.wdst[1] = Wkb;
  wa.wsrc[2] = Wv; wa.wdst[2] = Wvb;
  wa.wsrc[3] = Wo; wa.wdst[3] = Wob;
  hipLaunchKernelGGL(prepass, dim3(2080), dim3(256), 0, stream, gprob, mask, Gp, wa);

  // launch 2: fused Q/K/V projections
  GArgs gq;
  gq.A[0] = (const void*)query; gq.W[0] = Wqb; gq.bias[0] = bq; gq.C[0] = (void*)Qb; gq.mode[0] = 0; gq.osc[0] = CSC;
  gq.A[1] = (const void*)key_;  gq.W[1] = Wkb; gq.bias[1] = bk; gq.C[1] = (void*)Kb; gq.mode[1] = 0; gq.osc[1] = 1.0f;
  gq.A[2] = (const void*)value; gq.W[2] = Wvb; gq.bias[2] = bv; gq.C[2] = (void*)Vt; gq.mode[2] = 1; gq.osc[2] = 1.0f;
  hipLaunchKernelGGL((gemm_bn64<1>), dim3(32, 8, 3), dim3(256), 0, stream, gq);

  // launch 3: attention (1-D XCD-swizzled grid), writes X-layout partials
  hipLaunchKernelGGL(attn_split, dim3(1024), dim3(256), 0, stream, Qb, Kb, Vt, Gp, Pout, Pml);

  // launch 4: output projection with fused split-recombine
  hipLaunchKernelGGL(gemm_po, dim3(32, 8), dim3(256), 0, stream,
                     Pout, Pout + elems, Pml, Wob, bo, out);
}

// Round 20
// 89.264 us; speedup vs baseline: 1.0794x; 1.0270x over previous
//
#include <hip/hip_runtime.h>
#include <hip/hip_bf16.h>
#include <cstdint>
#include <cstddef>

typedef __attribute__((ext_vector_type(8))) short bf16x8;
typedef __attribute__((ext_vector_type(4))) float f32x4;
typedef __attribute__((address_space(3))) void lds_void;
typedef const __attribute__((address_space(1))) void g_void;

constexpr int Bc = 2, Sc = 2048, Dc = 512, Hc = 8, DKc = 64;
constexpr int SPLIT = 2;
constexpr int NKT = Sc / 64;           // 32 k-tiles total
constexpr int KT_PER = NKT / SPLIT;    // 16 per block
constexpr float CSC = 0.18033688011112042f;  // 0.125 * log2(e), folded into Q projection

struct alignas(16) us8 { unsigned short u[8]; };
struct alignas(8) us4 { unsigned short u[4]; };

__device__ __forceinline__ unsigned short f2bf(float x) {
  union { float f; unsigned int u; } v; v.f = x;
  unsigned int r = (v.u + 0x7FFFu + ((v.u >> 16) & 1u)) >> 16;
  return (unsigned short)r;
}

__device__ __forceinline__ float bf2f(unsigned short u) {
  union { unsigned int u; float f; } v; v.u = ((unsigned int)u) << 16;
  return v.f;
}

__device__ __forceinline__ us8 cvt8(float4 a, float4 b) {
  us8 o;
  o.u[0] = f2bf(a.x); o.u[1] = f2bf(a.y); o.u[2] = f2bf(a.z); o.u[3] = f2bf(a.w);
  o.u[4] = f2bf(b.x); o.u[5] = f2bf(b.y); o.u[6] = f2bf(b.z); o.u[7] = f2bf(b.w);
  return o;
}

// ---------------- prepass: g-permute via ASYNC-staged LDS tiles + weight fp32->bf16 ----------------
// blocks 0..2047: g tiles (gload_lds staging -> fragment gather -> coalesced permuted write);
// blocks 2048..2079: weight conversion.
struct WArgs { const float* wsrc[4]; unsigned short* wdst[4]; };

__global__ __launch_bounds__(256)
void prepass(const float* __restrict__ g, const int* __restrict__ m,
             unsigned short* __restrict__ gp, WArgs wa)
{
  __shared__ float Gs[64][64];   // 16 KB, XOR-swizzled granules (16B, phase (row&7)<<4)
  __shared__ int   Ms[64][64];   // 16 KB, same swizzle
  const int bx = blockIdx.x;
  const int tid = threadIdx.x;
  if (bx < 2048) {
    const int idx = bx;                 // b*1024 + qt*32 + kt
    const int b = idx >> 10, rest = idx & 1023, qt = rest >> 5, kt = rest & 31;
    const int q0 = qt * 64, k0t = kt * 64;
    const int lane = tid & 63, w = tid >> 6;

    // stage g + mask tiles (16 KB each) fully async: 8 gload_lds per lane, no VGPR pressure
#pragma unroll
    for (int i = 0; i < 4; ++i) {
      const int unit = w * 4 + i;                        // 0..15
      const int row = unit * 4 + (lane >> 4);            // 0..63
      const int cbyte = ((lane & 15) * 16) ^ ((row & 7) << 4);   // inverse-swizzled source col
      const size_t sbase = ((size_t)(b * Sc + q0 + row)) * Sc + k0t + (cbyte >> 2);
      __builtin_amdgcn_global_load_lds((g_void*)(g + sbase), (lds_void*)((char*)&Gs[0][0] + unit * 1024), 16, 0, 0);
      __builtin_amdgcn_global_load_lds((g_void*)(m + sbase), (lds_void*)((char*)&Ms[0][0] + unit * 1024), 16, 0, 0);
    }
    asm volatile("s_waitcnt vmcnt(0)" ::: "memory");
    __syncthreads();

    // gather permuted fragment (swizzled reads, even bank spread), cvt + LSB gate
    const int colb = tid & 15, hi = (tid >> 4) & 3, wid = tid >> 6;
    const int qr = wid * 16 + colb;
    const int q = q0 + qr;
    char* gb = (char*)&Gs[0][0];
    char* mb = (char*)&Ms[0][0];
    unsigned short vals[16];
#pragma unroll
    for (int n = 0; n < 4; ++n) {
      const int addr = qr * 256 + ((n * 64 + hi * 16) ^ ((qr & 7) << 4));
      float4 gv = *(const float4*)(gb + addr);
      int4 mv = *(const int4*)(mb + addr);
      const int kb = k0t + n * 16 + hi * 4;
      const float gg[4] = {gv.x, gv.y, gv.z, gv.w};
      const int mm[4] = {mv.x, mv.y, mv.z, mv.w};
#pragma unroll
      for (int rr = 0; rr < 4; ++rr) {
        const bool allowed = (mm[rr] != 0) || (kb + rr == q);
        vals[n * 4 + rr] = allowed ? (unsigned short)(f2bf(gg[rr]) | 1u) : (unsigned short)0;
      }
    }
    us8* o = (us8*)(gp + (((size_t)idx * 256) + tid) * 16);
    o[0] = *(us8*)&vals[0];
    o[1] = *(us8*)&vals[8];
  } else {
    const int r = bx - 2048;            // 0..31
    const int wi = r >> 3, sub = r & 7;
    const float* s = wa.wsrc[wi];
    unsigned short* d = wa.wdst[wi];
#pragma unroll
    for (int t = 0; t < 16; ++t) {
      const int i = sub * 4096 + t * 256 + tid;
      float4 a = ((const float4*)s)[(size_t)i * 2];
      float4 b2 = ((const float4*)s)[(size_t)i * 2 + 1];
      ((us8*)d)[i] = cvt8(a, b2);
    }
  }
}

// ---------------- 128x64-tile bf16 NT GEMM (W bf16 via gload_lds) ----------------
struct GArgs {
  const void* A[3];
  const unsigned short* W[3];
  const float* bias[3];
  void* C[3];
  int mode[3];
  float osc[3];
};

template<int A_FP32>
__global__ __launch_bounds__(256)
void gemm_bn64(GArgs ga)
{
  __shared__ unsigned short As[128][64];
  __shared__ unsigned short Bs[64][64];

  constexpr int K = 512, N = 512;
  const int z = blockIdx.z;
  const unsigned short* Wp = ga.W[z];
  const float* bias = ga.bias[z];
  const int mode = ga.mode[z];
  const float osc = ga.osc[z];

  const int tid = threadIdx.x, lane = tid & 63, w = tid >> 6;
  const int m0 = blockIdx.x * 128, n0 = blockIdx.y * 64;
  const int wm = w >> 1, wn = w & 1;
  const int colb = lane & 15, hi = lane >> 4, rowb = hi * 4;
  const int swz = (colb & 7) << 4;

  f32x4 acc[4][2];
#pragma unroll
  for (int i = 0; i < 4; ++i)
#pragma unroll
    for (int j = 0; j < 2; ++j) acc[i][j] = (f32x4){0.f, 0.f, 0.f, 0.f};

  const int lrow8 = lane >> 3;
  const int cb = ((lane & 7) * 16) ^ (lrow8 << 4);

  for (int k0 = 0; k0 < K; k0 += 64) {
    if (k0) __syncthreads();
#pragma unroll
    for (int i = 0; i < 2; ++i) {
      const int u = w + i * 4;
      const int row = u * 8 + lrow8;
      const unsigned short* bsrc = Wp + (size_t)(n0 + row) * K + k0 + (cb >> 1);
      __builtin_amdgcn_global_load_lds((g_void*)bsrc, (lds_void*)((char*)&Bs[0][0] + u * 1024), 16, 0, 0);
    }
    if (A_FP32) {
      const float* Af = (const float*)ga.A[z];
#pragma unroll
      for (int i = 0; i < 4; ++i) {
        const int u = w * 4 + i;
        const int row = u * 8 + lrow8;
        const float* src = Af + (size_t)(m0 + row) * K + k0 + (cb >> 1);
        float4 v0 = *(const float4*)src, v1 = *(const float4*)(src + 4);
        *(us8*)((char*)&As[0][0] + u * 1024 + lane * 16) = cvt8(v0, v1);
      }
    } else {
      const unsigned short* Ab = (const unsigned short*)ga.A[z];
#pragma unroll
      for (int i = 0; i < 4; ++i) {
        const int u = w * 4 + i;
        const int row = u * 8 + lrow8;
        const unsigned short* asrc = Ab + (size_t)(m0 + row) * K + k0 + (cb >> 1);
        __builtin_amdgcn_global_load_lds((g_void*)asrc, (lds_void*)((char*)&As[0][0] + u * 1024), 16, 0, 0);
      }
    }
    asm volatile("s_waitcnt vmcnt(0)" ::: "memory");
    __syncthreads();

    char* ab = (char*)&As[0][0];
    char* bb = (char*)&Bs[0][0];
#pragma unroll
    for (int kk = 0; kk < 2; ++kk) {
      bf16x8 af[4], bfr[2];
#pragma unroll
      for (int mf = 0; mf < 4; ++mf) {
        const int ar = wm * 64 + mf * 16 + colb;
        af[mf] = *(const bf16x8*)(ab + ar * 128 + ((kk * 64 + hi * 16) ^ swz));
      }
#pragma unroll
      for (int nf = 0; nf < 2; ++nf) {
        const int br = wn * 32 + nf * 16 + colb;
        bfr[nf] = *(const bf16x8*)(bb + br * 128 + ((kk * 64 + hi * 16) ^ swz));
      }
      __builtin_amdgcn_s_setprio(1);
#pragma unroll
      for (int mf = 0; mf < 4; ++mf)
#pragma unroll
        for (int nf = 0; nf < 2; ++nf)
          acc[mf][nf] = __builtin_amdgcn_mfma_f32_16x16x32_bf16(af[mf], bfr[nf], acc[mf][nf], 0, 0, 0);
      __builtin_amdgcn_s_setprio(0);
    }
  }

#pragma unroll
  for (int nf = 0; nf < 2; ++nf) {
    const int gn = n0 + wn * 32 + nf * 16 + colb;
    const float bv = bias[gn];
    if (mode == 1) {
      unsigned short* Cp = (unsigned short*)ga.C[z];
#pragma unroll
      for (int mf = 0; mf < 4; ++mf) {
        const int gm = m0 + wm * 64 + mf * 16 + rowb;
        const int bb_ = gm >> 11, ss = gm & (Sc - 1);
        us4 vv;
#pragma unroll
        for (int rr = 0; rr < 4; ++rr) vv.u[rr] = f2bf(acc[mf][nf][rr] + bv);
        *(us4*)(Cp + ((size_t)bb_ * N + gn) * Sc + ss) = vv;
      }
    } else if (mode == 0) {
      unsigned short* Cp = (unsigned short*)ga.C[z];
#pragma unroll
      for (int mf = 0; mf < 4; ++mf)
#pragma unroll
        for (int rr = 0; rr < 4; ++rr) {
          const int gm = m0 + wm * 64 + mf * 16 + rowb + rr;
          Cp[(size_t)gm * N + gn] = f2bf((acc[mf][nf][rr] + bv) * osc);
        }
    } else {
      float* Cp = (float*)ga.C[z];
#pragma unroll
      for (int mf = 0; mf < 4; ++mf)
#pragma unroll
        for (int rr = 0; rr < 4; ++rr) {
          const int gm = m0 + wm * 64 + mf * 16 + rowb + rr;
          Cp[(size_t)gm * N + gn] = acc[mf][nf][rr] + bv;
        }
    }
  }
}

// ---------------- split-K flash attention: fixed-shift softmax + XCD swizzle + static dbuf ----------------
// 1-D grid of 1024; wgid decode co-locates the 16 blocks of one (b,qt) g-group on one XCD.
// Partials: Pacc[blk][d=64][q=64] bf16 (O^T), Pml[blk][64] = l (fp32).
__global__ __launch_bounds__(256, 4)
void attn_split(const unsigned short* __restrict__ Qb,
                const unsigned short* __restrict__ Kb,
                const unsigned short* __restrict__ Vt,
                const unsigned short* __restrict__ Gp,
                unsigned short* __restrict__ Pacc,
                float* __restrict__ Pml)
{
  __shared__ unsigned short Ks[2][64][64];   // [k][dk], XOR-swizzled rows
  __shared__ unsigned short Vs[2][64][64];   // [dk][k], XOR-swizzled rows
  __shared__ unsigned short Ps[4][16][64];   // per-wave P [q][k], XOR-swizzled rows

  const int tid = threadIdx.x, lane = tid & 63, wid = tid >> 6;
  const int wgid = blockIdx.x;
  const int xcd = wgid & 7, rest = wgid >> 3;
  const int mem = rest & 15, ghi = rest >> 4;
  const int g = ghi * 8 + xcd;                // 0..63
  const int b = g >> 5, qt = g & 31;
  const int h = mem >> 1, sp = mem & 1;
  const int bh = b * 8 + h;
  const int q0 = qt * 64;
  const int kt0 = sp * KT_PER;

  const int colb = lane & 15;
  const int hi = lane >> 4;
  const int rowb = hi * 4;
  const int c3s = (colb & 7) << 4;

  bf16x8 qf[2];
  {
    const unsigned short* qp = Qb + ((size_t)(b * Sc + q0 + wid * 16 + colb) * Dc + h * DKc + hi * 8);
    qf[0] = *(const bf16x8*)qp;
    qf[1] = *(const bf16x8*)(qp + 32);
  }

  f32x4 acc[4] = {{0,0,0,0},{0,0,0,0},{0,0,0,0},{0,0,0,0}};   // acc[n][rr] = O^T[n*16+rowb+rr][q]
  float lr0 = 0.f, lr1 = 0.f, lr2 = 0.f, lr3 = 0.f;            // tree-split l partials

  auto stageKV = [&](int bufI, int kt) {
    const int k0 = kt * 64;
#pragma unroll
    for (int i = 0; i < 2; ++i) {
      const int obase = wid * 1024 + i * 4096;
      const int row = (obase >> 7) + (lane >> 3);
      const int cb = ((lane & 7) * 16) ^ ((row & 7) << 4);
      const unsigned short* ksrc = Kb + (size_t)(b * Sc + k0 + row) * Dc + h * DKc + (cb >> 1);
      const unsigned short* vsrc = Vt + ((size_t)b * Dc + h * DKc + row) * Sc + k0 + (cb >> 1);
      __builtin_amdgcn_global_load_lds((g_void*)ksrc, (lds_void*)((char*)&Ks[bufI][0][0] + obase), 16, 0, 0);
      __builtin_amdgcn_global_load_lds((g_void*)vsrc, (lds_void*)((char*)&Vs[bufI][0][0] + obase), 16, 0, 0);
    }
  };

  const unsigned short* gtile = Gp + (((size_t)(b * 1024 + qt * 32)) * 256 + tid) * 16;
  auto loadG = [&](int kt, us8& g0, us8& g1) {
    const us8* p = (const us8*)(gtile + (size_t)kt * 4096);
    g0 = p[0]; g1 = p[1];
  };

  us8 gA0, gA1, gB0, gB1;
  stageKV(0, kt0);
  loadG(kt0, gA0, gA1);
  asm volatile("s_waitcnt vmcnt(0)" ::: "memory");
  __syncthreads();

  char* psbase = (char*)&Ps[wid][0][0];

  auto doTile = [&](int kt, int bufI, us8& gc0, us8& gc1, us8& gn0, us8& gn1) {
    if (kt + 1 < kt0 + KT_PER) {
      stageKV(bufI ^ 1, kt + 1);
      loadG(kt + 1, gn0, gn1);
    }

    // S^T = K Q^T : sf[n][rr] = S[q=colb][k = n*16 + hi*4 + rr]  (CSC pre-scaled via Q)
    f32x4 sf[4] = {{0,0,0,0},{0,0,0,0},{0,0,0,0},{0,0,0,0}};
    char* ksb = (char*)&Ks[bufI][0][0];
    __builtin_amdgcn_s_setprio(1);
#pragma unroll
    for (int kk = 0; kk < 2; ++kk) {
#pragma unroll
      for (int n = 0; n < 4; ++n) {
        const int krow = n * 16 + colb;
        bf16x8 kf = *(const bf16x8*)(ksb + krow * 128 + ((kk * 64 + hi * 16) ^ ((krow & 7) << 4)));
        sf[n] = __builtin_amdgcn_mfma_f32_16x16x32_bf16(kf, qf[kk], sf[n], 0, 0, 0);
      }
    }
    __builtin_amdgcn_s_setprio(0);

    // fixed-shift softmax: p = exp2(s2); gating via g LSB; l in 4 independent partials
    unsigned int pw[8];
#pragma unroll
    for (int n = 0; n < 4; ++n) {
      float lacc = 0.f;
#pragma unroll
      for (int s2 = 0; s2 < 2; ++s2) {
        const int jv = n * 4 + s2 * 2;
        const unsigned short u0 = (jv < 8) ? gc0.u[jv] : gc1.u[jv - 8];
        const unsigned short u1 = (jv + 1 < 8) ? gc0.u[jv + 1] : gc1.u[jv + 1 - 8];
        const float p0 = __builtin_amdgcn_exp2f(sf[n][s2 * 2]);
        const float p1 = __builtin_amdgcn_exp2f(sf[n][s2 * 2 + 1]);
        lacc = fmaf(p0, (float)(u0 & 1u), lacc);
        lacc = fmaf(p1, (float)(u1 & 1u), lacc);
        const float q0v = p0 * bf2f(u0), q1v = p1 * bf2f(u1);
        asm("v_cvt_pk_bf16_f32 %0, %1, %2" : "=v"(pw[n * 2 + s2]) : "v"(q0v), "v"(q1v));
      }
      if (n == 0) lr0 += lacc; else if (n == 1) lr1 += lacc;
      else if (n == 2) lr2 += lacc; else lr3 += lacc;
    }

    // store P [q=colb][k] as 4x ds_write_b64
#pragma unroll
    for (int n = 0; n < 4; ++n) {
      const unsigned long long w64 = ((unsigned long long)pw[n * 2 + 1] << 32) | pw[n * 2];
      *(unsigned long long*)(psbase + colb * 128 + ((n * 32 + hi * 8) ^ c3s)) = w64;
    }

    // acc += V^T P^T  (O^T layout; Ps wave-private)
    char* vsb = (char*)&Vs[bufI][0][0];
    __builtin_amdgcn_s_setprio(1);
#pragma unroll
    for (int kk = 0; kk < 2; ++kk) {
      bf16x8 pf = *(const bf16x8*)(psbase + colb * 128 + ((kk * 64 + hi * 16) ^ c3s));
#pragma unroll
      for (int n = 0; n < 4; ++n) {
        const int vrow = n * 16 + colb;
        bf16x8 vf = *(const bf16x8*)(vsb + vrow * 128 + ((kk * 64 + hi * 16) ^ ((vrow & 7) << 4)));
        acc[n] = __builtin_amdgcn_mfma_f32_16x16x32_bf16(vf, pf, acc[n], 0, 0, 0);
      }
    }
    __builtin_amdgcn_s_setprio(0);

    asm volatile("s_waitcnt vmcnt(0)" ::: "memory");
    __syncthreads();
  };

  for (int j = 0; j < KT_PER; j += 2) {
    doTile(kt0 + j,     0, gA0, gA1, gB0, gB1);
    doTile(kt0 + j + 1, 1, gB0, gB1, gA0, gA1);
  }

  // epilogue: combine l partials, cross-lane reduce
  float lrun = (lr0 + lr1) + (lr2 + lr3);
  lrun += __shfl_xor(lrun, 16);
  lrun += __shfl_xor(lrun, 32);

  // write partials (O^T layout: [d][q]) as bf16
  const size_t blin = ((size_t)bh * 32 + qt) * SPLIT + sp;
  unsigned short* pa = Pacc + blin * 4096;
#pragma unroll
  for (int n = 0; n < 4; ++n)
#pragma unroll
    for (int rr = 0; rr < 4; ++rr)
      pa[(size_t)(n * 16 + rowb + rr) * 64 + wid * 16 + colb] = f2bf(acc[n][rr]);
  if (hi == 0) Pml[blin * 64 + wid * 16 + colb] = lrun;
}

// ---------------- recombine split partials -> bf16 X (plain sum; fixed shift) ----------------
__global__ __launch_bounds__(256)
void attn_reduce(const unsigned short* __restrict__ Pacc, const float* __restrict__ Pml,
                 unsigned short* __restrict__ Xb)
{
  const int gidx = blockIdx.x;      // bh*32 + qt
  const int bh = gidx >> 5, qt = gidx & 31;
  const int b = bh >> 3, h = bh & 7;
  const int tid = threadIdx.x;
  const int qi = tid & 63;
  const int d0 = (tid >> 6) * 16;
  const size_t pb = (size_t)gidx * SPLIT;

  float denom = 0.f;
#pragma unroll
  for (int s = 0; s < SPLIT; ++s) denom += Pml[(pb + s) * 64 + qi];
  const float inv = 1.0f / denom;

  unsigned short vals[16];
#pragma unroll
  for (int j = 0; j < 16; ++j) {
    float a = 0.f;
#pragma unroll
    for (int s = 0; s < SPLIT; ++s)
      a += bf2f(Pacc[(pb + s) * 4096 + (size_t)(d0 + j) * 64 + qi]);
    vals[j] = f2bf(a * inv);
  }
  unsigned short* xp = Xb + ((size_t)(b * Sc) + qt * 64 + qi) * Dc + h * DKc + d0;
  *(us8*)xp = *(us8*)&vals[0];
  *(us8*)(xp + 8) = *(us8*)&vals[8];
}

extern "C" void kernel_launch(void* const* d_in, const int* in_sizes, int n_in,
                              void* d_out, int out_size, void* d_ws, size_t ws_size,
                              hipStream_t stream)
{
  const float* query = (const float*)d_in[0];
  const float* key_  = (const float*)d_in[1];
  const float* value = (const float*)d_in[2];
  const float* gprob = (const float*)d_in[3];
  const int*   mask  = (const int*)d_in[4];
  const float* Wq = (const float*)d_in[5];
  const float* bq = (const float*)d_in[6];
  const float* Wk = (const float*)d_in[7];
  const float* bk = (const float*)d_in[8];
  const float* Wv = (const float*)d_in[9];
  const float* bv = (const float*)d_in[10];
  const float* Wo = (const float*)d_in[11];
  const float* bo = (const float*)d_in[12];
  float* out = (float*)d_out;

  const size_t elems = (size_t)Bc * Sc * Dc;     // 2 Mi
  const size_t gelems = (size_t)Bc * Sc * Sc;    // 8 Mi
  const size_t welems = (size_t)Dc * Dc;         // 256 Ki

  char* base = (char*)d_ws;
  unsigned short* Qb = (unsigned short*)(base);                    // 4 MB
  unsigned short* Kb = Qb + elems;                                 // 4 MB
  unsigned short* Vt = Kb + elems;                                 // 4 MB
  unsigned short* Xb = Vt + elems;                                 // 4 MB
  unsigned short* Gp = Xb + elems;                                 // 16.8 MB
  unsigned short* Wqb = Gp + gelems;                               // 4 x 0.5 MB bf16 weights
  unsigned short* Wkb = Wqb + welems;
  unsigned short* Wvb = Wkb + welems;
  unsigned short* Wob = Wvb + welems;
  unsigned short* Pacc = Wob + welems;                             // 8.4 MB bf16 partials
  float* Pml = (float*)(Pacc + (size_t)(Bc * Hc) * 32 * SPLIT * 4096);  // 0.26 MB

  // fused prepass: permuted g_eff (async-staged) + weight conversions
  WArgs wa;
  wa.wsrc[0] = Wq; wa.wdst[0] = Wqb;
  wa.wsrc[1] = Wk; wa.wdst[1] = Wkb;
  wa.wsrc[2] = Wv; wa.wdst[2] = Wvb;
  wa.wsrc[3] = Wo; wa.wdst[3] = Wob;
  hipLaunchKernelGGL(prepass, dim3(2080), dim3(256), 0, stream, gprob, mask, Gp, wa);

  // fused Q/K/V projections: fp32 A reg-staged, bf16 W via gload_lds; Q pre-scaled by CSC
  GArgs gq;
  gq.A[0] = (const void*)query; gq.W[0] = Wqb; gq.bias[0] = bq; gq.C[0] = (void*)Qb; gq.mode[0] = 0; gq.osc[0] = CSC;
  gq.A[1] = (const void*)key_;  gq.W[1] = Wkb; gq.bias[1] = bk; gq.C[1] = (void*)Kb; gq.mode[1] = 0; gq.osc[1] = 1.0f;
  gq.A[2] = (const void*)value; gq.W[2] = Wvb; gq.bias[2] = bv; gq.C[2] = (void*)Vt; gq.mode[2] = 1; gq.osc[2] = 1.0f;
  hipLaunchKernelGGL((gemm_bn64<1>), dim3(32, 8, 3), dim3(256), 0, stream, gq);

  // attention: 1-D XCD-swizzled grid (1024 blocks)
  hipLaunchKernelGGL(attn_split, dim3(1024), dim3(256), 0, stream, Qb, Kb, Vt, Gp, Pacc, Pml);
  hipLaunchKernelGGL(attn_reduce, dim3(Bc * Hc * 32), dim3(256), 0, stream, Pacc, Pml, Xb);

  // output projection: bf16 A via global_load_lds
  GArgs go;
  go.A[0] = (const void*)Xb; go.W[0] = Wob; go.bias[0] = bo; go.C[0] = (void*)out; go.mode[0] = 2; go.osc[0] = 1.0f;
  go.A[1] = go.A[0]; go.W[1] = go.W[0]; go.bias[1] = go.bias[0]; go.C[1] = go.C[0]; go.mode[1] = 2; go.osc[1] = 1.0f;
  go.A[2] = go.A[0]; go.W[2] = go.W[0]; go.bias[2] = go.bias[0]; go.C[2] = go.C[0]; go.mode[2] = 2; go.osc[2] = 1.0f;
  hipLaunchKernelGGL((gemm_bn64<0>), dim3(32, 8, 1), dim3(256), 0, stream, go);
}